// Round 12
// baseline (233.111 us; speedup 1.0000x reference)
//
#include <hip/hip_runtime.h>
#include <hip/hip_bf16.h>

#define BB 4096
#define SZ 32
#define DD 10000
#define DPAD 10240
#define NMOD 64
#define NROWS_B 192   // cluster(64) + Mh(64) + Ml(64)
#define KSPLIT 4
#define KSEG 2560     // DPAD / KSPLIT
#define NWORDS 160    // DPAD/64 packed words per row

// ws layout (bytes)
#define WS_BMAT_OFF   0u
#define WS_PACK_OFF   (4u << 20)                 // 5.24 MB of packed bits
#define WS_CPART_OFF  (9437184u)                 // 4*4096*192*4 = 12.6 MB

typedef __attribute__((ext_vector_type(4))) float f32x4;
typedef __attribute__((ext_vector_type(8))) short short8;

static __device__ __forceinline__ ushort f2bf(float f) {
    unsigned u = __builtin_bit_cast(unsigned, f);
    unsigned r = (u + 0x7fffu + ((u >> 16) & 1u)) >> 16;   // RNE
    return (ushort)r;
}

// sign pipeline: 1 iff cosf(t+bk)*sinf(t) > 0, else 0 (covers ==0 -> -1).
static __device__ __forceinline__ int sign_pm(float t, float bk) {
    if (t == 0.0f) return 0;                 // sin(+-0)=+-0 -> sample==+-0 -> -1
    const double INV_PI_D = 0.31830988618379067153776752674503;
    float v = t + bk;
    long long n1 = (long long)floor((double)t * INV_PI_D);
    long long n2 = (long long)floor(fma((double)v, INV_PI_D, 0.5));
    return (int)(((n1 + n2) & 1LL) ^ 1LL);   // 1 -> +1, 0 -> -1
}

// ---------------- K0: build Bmat [192][10240] bf16 ----------------
__global__ __launch_bounds__(256) void k0_build_B(
        const float* __restrict__ M, const float* __restrict__ cluster,
        ushort* __restrict__ Bmat) {
    int k = blockIdx.x * 256 + threadIdx.x;   // 0..10239
    int row = blockIdx.y;                      // 0..191
    ushort u = 0;
    if (k < DD) {
        if (row < 64) {
            u = f2bf(cluster[row * DD + k]);
        } else {
            float m = M[(row & 63) * DD + k];
            ushort mh = f2bf(m);
            if (row < 128) {
                u = mh;
            } else {
                float mhf = __builtin_bit_cast(float, (unsigned)mh << 16);
                u = f2bf(m - mhf);
            }
        }
    }
    Bmat[row * DPAD + k] = u;
}

// ---------------- K1: encode (T_G ordering) -> enc f32 + packed bits ------
__global__ __launch_bounds__(256) void k1_enc(
        const float* __restrict__ x, const float* __restrict__ W,
        const float* __restrict__ bias, float* __restrict__ enc_out,
        unsigned long long* __restrict__ packed) {
    __shared__ float xs[64 * SZ];
    const int tid = threadIdx.x;
    const int i0 = blockIdx.y * 64;
    const int k = blockIdx.x * 256 + tid;
    const bool valid = (k < DD);
    const int lane = tid & 63;
    const int word = blockIdx.x * 4 + (tid >> 6);  // packed word index 0..159

    {
        const float4* xg = reinterpret_cast<const float4*>(x + (size_t)i0 * SZ);
        float4* xs4 = reinterpret_cast<float4*>(xs);
        xs4[tid] = xg[tid];
        xs4[tid + 256] = xg[tid + 256];
    }
    const int kw = valid ? k : 0;
    float4 w4[8];
    {
        const float4* wg = reinterpret_cast<const float4*>(W) + (size_t)kw * 8;
        #pragma unroll
        for (int c = 0; c < 8; ++c) w4[c] = wg[c];
    }
    const float bk = bias[kw];
    __syncthreads();

    for (int i = 0; i < 64; ++i) {
        const float4* xr = reinterpret_cast<const float4*>(xs + i * SZ);
        float g0 = 0.f, g1 = 0.f, g2 = 0.f, g3 = 0.f;
        #pragma unroll
        for (int c = 0; c < 8; ++c) {
            float4 xc = xr[c];   // LDS broadcast (uniform address)
            g0 = fmaf(w4[c].x, xc.x, g0);
            g1 = fmaf(w4[c].y, xc.y, g1);
            g2 = fmaf(w4[c].z, xc.z, g2);
            g3 = fmaf(w4[c].w, xc.w, g3);
        }
        float t = (g0 + g1) + (g2 + g3);
        int e = sign_pm(t, bk);
        unsigned long long m = __ballot(e);
        if (valid) enc_out[(size_t)(i0 + i) * DD + k] = e ? 1.f : -1.f;
        if (lane == 0) packed[(size_t)(i0 + i) * NWORDS + word] = m;
    }
}

// ---------------- K2: C[seg] = enc @ Bmat^T (bf16 MFMA, packed A) ---------
// 256 blocks (64 row-tiles x 4 segs), 256 threads. Reg-prefetch + XOR-swizzle.
__global__ __launch_bounds__(256) void k2_gemm(
        const unsigned* __restrict__ packed32,   // [4096][320] u32 view
        const ushort* __restrict__ Bmat,
        float* __restrict__ Cpart) {
    __shared__ __align__(16) ushort As[64 * 72];
    __shared__ __align__(16) ushort Bs[NROWS_B * 72];

    const int tid = threadIdx.x;
    const int row0 = blockIdx.x * 64;
    const int seg = blockIdx.y;

    const int lane = tid & 63;
    const int wid = tid >> 6;
    const int wrow = (wid & 1) * 32;
    const int wcol = (wid >> 1) * 96;
    const int fr = lane & 15;
    const int fg = lane >> 4;

    const int arow = tid >> 2;          // 0..63 (A-expand row)
    const int nib = tid & 3;            // 16-bit group within 64-bit word

    f32x4 acc[2][6] = {};

    unsigned pa;                         // 16 A-bits
    uint4 pb[6];                         // B stage (24 KB / 256 threads)

    const int wbase = seg * 40;          // packed word base for this seg

    // ---- prefetch step 0
    {
        unsigned v = packed32[(size_t)(row0 + arow) * (NWORDS * 2) + wbase * 2 + (nib >> 1)];
        pa = (v >> ((nib & 1) * 16)) & 0xffffu;
        const int kk0 = seg * KSEG;
        #pragma unroll
        for (int s = 0; s < 6; ++s) {
            int task = s * 256 + tid;
            int brow = task >> 3;
            int bch = (task & 7) * 8;
            pb[s] = *reinterpret_cast<const uint4*>(Bmat + (size_t)brow * DPAD + kk0 + bch);
        }
    }

    for (int step = 0; step < 40; ++step) {
        __syncthreads();
        // ---- A expand: 16 bits -> 16 bf16, two swizzled b128 stores
        {
            unsigned d[8];
            #pragma unroll
            for (int j = 0; j < 8; ++j) {
                unsigned lo = (pa >> (2 * j)) & 1u;
                unsigned hi = (pa >> (2 * j + 1)) & 1u;
                d[j] = (lo ? 0x3F80u : 0xBF80u) | ((hi ? 0x3F80u : 0xBF80u) << 16);
            }
            int s0 = ((nib * 2) ^ (arow & 7)) * 8;
            int s1 = ((nib * 2 + 1) ^ (arow & 7)) * 8;
            *reinterpret_cast<uint4*>(&As[arow * 72 + s0]) = make_uint4(d[0], d[1], d[2], d[3]);
            *reinterpret_cast<uint4*>(&As[arow * 72 + s1]) = make_uint4(d[4], d[5], d[6], d[7]);
        }
        // ---- B write (swizzled)
        #pragma unroll
        for (int s = 0; s < 6; ++s) {
            int task = s * 256 + tid;
            int brow = task >> 3;
            int slot = ((task & 7) ^ (brow & 7)) * 8;
            *reinterpret_cast<uint4*>(&Bs[brow * 72 + slot]) = pb[s];
        }
        // ---- prefetch step+1 (latency hides under MFMA below)
        if (step + 1 < 40) {
            unsigned v = packed32[(size_t)(row0 + arow) * (NWORDS * 2) + (wbase + step + 1) * 2 + (nib >> 1)];
            pa = (v >> ((nib & 1) * 16)) & 0xffffu;
            const int kk0 = seg * KSEG + (step + 1) * 64;
            #pragma unroll
            for (int s = 0; s < 6; ++s) {
                int task = s * 256 + tid;
                int brow = task >> 3;
                int bch = (task & 7) * 8;
                pb[s] = *reinterpret_cast<const uint4*>(Bmat + (size_t)brow * DPAD + kk0 + bch);
            }
        }
        __syncthreads();
        // ---- MFMA (swizzled reads)
        #pragma unroll
        for (int h = 0; h < 2; ++h) {
            int ar0 = wrow + fr;
            int ar1 = wrow + 16 + fr;
            int asl = ((h * 4 + fg) ^ (ar0 & 7)) * 8;   // (ar1&7)==(ar0&7)
            short8 a0 = *reinterpret_cast<const short8*>(&As[ar0 * 72 + asl]);
            short8 a1 = *reinterpret_cast<const short8*>(&As[ar1 * 72 + asl]);
            #pragma unroll
            for (int n = 0; n < 6; ++n) {
                int brow = wcol + n * 16 + fr;
                int bsl = ((h * 4 + fg) ^ (brow & 7)) * 8;
                short8 bb = *reinterpret_cast<const short8*>(&Bs[brow * 72 + bsl]);
                acc[0][n] = __builtin_amdgcn_mfma_f32_16x16x32_bf16(a0, bb, acc[0][n], 0, 0, 0);
                acc[1][n] = __builtin_amdgcn_mfma_f32_16x16x32_bf16(a1, bb, acc[1][n], 0, 0, 0);
            }
        }
    }

    // ---- epilogue: D col=lane&15, row=(lane>>4)*4+reg
    #pragma unroll
    for (int m = 0; m < 2; ++m)
        #pragma unroll
        for (int n = 0; n < 6; ++n)
            #pragma unroll
            for (int r = 0; r < 4; ++r) {
                int grow = row0 + wrow + m * 16 + fg * 4 + r;
                int col = wcol + n * 16 + fr;
                Cpart[((size_t)seg * BB + grow) * NROWS_B + col] = acc[m][n][r];
            }
}

// ---------------- K3: reduce partials + softmax + combine ----------------
__global__ __launch_bounds__(256) void k3_final(
        const float* __restrict__ Cpart, float* __restrict__ res) {
    const int wid = threadIdx.x >> 6;
    const int lane = threadIdx.x & 63;
    const int row = blockIdx.x * 4 + wid;

    float s = 0.f, mh = 0.f, ml = 0.f;
    #pragma unroll
    for (int seg = 0; seg < KSPLIT; ++seg) {
        const float* base = Cpart + ((size_t)seg * BB + row) * NROWS_B;
        s += base[lane];
        mh += base[64 + lane];
        ml += base[128 + lane];
    }
    float sim = s * 1e-4f;          // exact norms: 100 * 100
    float mr = mh + ml;

    float mx = sim;
    #pragma unroll
    for (int o = 32; o; o >>= 1) mx = fmaxf(mx, __shfl_xor(mx, o, 64));
    float e = expf(sim - mx);
    float num = e * mr;
    float Z = e;
    #pragma unroll
    for (int o = 32; o; o >>= 1) {
        Z += __shfl_xor(Z, o, 64);
        num += __shfl_xor(num, o, 64);
    }
    if (lane == 0) res[row] = num / Z;
}

extern "C" void kernel_launch(void* const* d_in, const int* in_sizes, int n_in,
                              void* d_out, int out_size, void* d_ws, size_t ws_size,
                              hipStream_t stream) {
    const float* x = (const float*)d_in[0];
    const float* W = (const float*)d_in[1];
    const float* bias = (const float*)d_in[2];
    const float* M = (const float*)d_in[3];
    const float* cluster = (const float*)d_in[4];

    float* res = (float*)d_out;            // [4096]
    float* enc = (float*)d_out + BB;       // [4096][10000]

    ushort* Bmat = (ushort*)((char*)d_ws + WS_BMAT_OFF);              // 3.93 MB
    unsigned long long* packed = (unsigned long long*)((char*)d_ws + WS_PACK_OFF);  // 5.24 MB
    float* Cpart = (float*)((char*)d_ws + WS_CPART_OFF);              // 12.6 MB

    k0_build_B<<<dim3(40, 192), 256, 0, stream>>>(M, cluster, Bmat);
    k1_enc<<<dim3(40, 64), 256, 0, stream>>>(x, W, bias, enc, packed);
    k2_gemm<<<dim3(64, KSPLIT), 256, 0, stream>>>((const unsigned*)packed, Bmat, Cpart);
    k3_final<<<BB / 4, 256, 0, stream>>>(Cpart, res);
}

// Round 13
// 215.414 us; speedup vs baseline: 1.0822x; 1.0822x over previous
//
#include <hip/hip_runtime.h>
#include <hip/hip_bf16.h>

#define BB 4096
#define SZ 32
#define DD 10000
#define DPAD 10240
#define NMOD 64
#define NROWS_B 192   // cluster(64) + Mh(64) + Ml(64)
#define KSPLIT 4
#define KSEG 2560     // DPAD / KSPLIT
#define NWORDS 160    // DPAD/64 packed words per row
#define STEPS 40      // KSEG/64

// ws layout (bytes)
#define WS_BMAT_OFF   0u
#define WS_PACK_OFF   (4u << 20)                 // 5.24 MB of packed bits
#define WS_CPART_OFF  (9437184u)                 // 4*4096*192*4 = 12.6 MB

typedef __attribute__((ext_vector_type(4))) float f32x4;
typedef __attribute__((ext_vector_type(8))) short short8;

static __device__ __forceinline__ ushort f2bf(float f) {
    unsigned u = __builtin_bit_cast(unsigned, f);
    unsigned r = (u + 0x7fffu + ((u >> 16) & 1u)) >> 16;   // RNE
    return (ushort)r;
}

// sign pipeline: 1 iff cosf(t+bk)*sinf(t) > 0, else 0 (covers ==0 -> -1).
static __device__ __forceinline__ int sign_pm(float t, float bk) {
    if (t == 0.0f) return 0;                 // sin(+-0)=+-0 -> sample==+-0 -> -1
    const double INV_PI_D = 0.31830988618379067153776752674503;
    float v = t + bk;
    long long n1 = (long long)floor((double)t * INV_PI_D);
    long long n2 = (long long)floor(fma((double)v, INV_PI_D, 0.5));
    return (int)(((n1 + n2) & 1LL) ^ 1LL);   // 1 -> +1, 0 -> -1
}

// expand 8 packed bits (bit=1 -> +1.0bf16, 0 -> -1.0bf16) into short8
static __device__ __forceinline__ short8 expand8(unsigned b) {
    unsigned nb = ~b;
    unsigned r0 = 0x3F803F80u | ((nb & 1u) << 15) | ((nb & 2u) << 30);
    unsigned r1 = 0x3F803F80u | (((nb >> 2) & 1u) << 15) | (((nb >> 2) & 2u) << 30);
    unsigned r2 = 0x3F803F80u | (((nb >> 4) & 1u) << 15) | (((nb >> 4) & 2u) << 30);
    unsigned r3 = 0x3F803F80u | (((nb >> 6) & 1u) << 15) | (((nb >> 6) & 2u) << 30);
    uint4 u = make_uint4(r0, r1, r2, r3);
    return __builtin_bit_cast(short8, u);
}

// ---------------- K0: build Bmat [192][10240] bf16 ----------------
__global__ __launch_bounds__(256) void k0_build_B(
        const float* __restrict__ M, const float* __restrict__ cluster,
        ushort* __restrict__ Bmat) {
    int k = blockIdx.x * 256 + threadIdx.x;   // 0..10239
    int row = blockIdx.y;                      // 0..191
    ushort u = 0;
    if (k < DD) {
        if (row < 64) {
            u = f2bf(cluster[row * DD + k]);
        } else {
            float m = M[(row & 63) * DD + k];
            ushort mh = f2bf(m);
            if (row < 128) {
                u = mh;
            } else {
                float mhf = __builtin_bit_cast(float, (unsigned)mh << 16);
                u = f2bf(m - mhf);
            }
        }
    }
    Bmat[row * DPAD + k] = u;
}

// ---------------- K1: encode (T_G ordering) -> enc f32 + packed bits ------
__global__ __launch_bounds__(256) void k1_enc(
        const float* __restrict__ x, const float* __restrict__ W,
        const float* __restrict__ bias, float* __restrict__ enc_out,
        unsigned long long* __restrict__ packed) {
    __shared__ float xs[64 * SZ];
    const int tid = threadIdx.x;
    const int i0 = blockIdx.y * 64;
    const int k = blockIdx.x * 256 + tid;
    const bool valid = (k < DD);
    const int lane = tid & 63;
    const int word = blockIdx.x * 4 + (tid >> 6);  // packed word index 0..159

    {
        const float4* xg = reinterpret_cast<const float4*>(x + (size_t)i0 * SZ);
        float4* xs4 = reinterpret_cast<float4*>(xs);
        xs4[tid] = xg[tid];
        xs4[tid + 256] = xg[tid + 256];
    }
    const int kw = valid ? k : 0;
    float4 w4[8];
    {
        const float4* wg = reinterpret_cast<const float4*>(W) + (size_t)kw * 8;
        #pragma unroll
        for (int c = 0; c < 8; ++c) w4[c] = wg[c];
    }
    const float bk = bias[kw];
    __syncthreads();

    for (int i = 0; i < 64; ++i) {
        const float4* xr = reinterpret_cast<const float4*>(xs + i * SZ);
        float g0 = 0.f, g1 = 0.f, g2 = 0.f, g3 = 0.f;
        #pragma unroll
        for (int c = 0; c < 8; ++c) {
            float4 xc = xr[c];   // LDS broadcast (uniform address)
            g0 = fmaf(w4[c].x, xc.x, g0);
            g1 = fmaf(w4[c].y, xc.y, g1);
            g2 = fmaf(w4[c].z, xc.z, g2);
            g3 = fmaf(w4[c].w, xc.w, g3);
        }
        float t = (g0 + g1) + (g2 + g3);
        int e = sign_pm(t, bk);
        unsigned long long m = __ballot(e);
        if (valid) enc_out[(size_t)(i0 + i) * DD + k] = e ? 1.f : -1.f;
        if (lane == 0) packed[(size_t)(i0 + i) * NWORDS + word] = m;
    }
}

// ---------------- K2: fragment-direct MFMA GEMM (no LDS, no barriers) -----
// grid (64 row-tiles, 8 = seg*2+colhalf), 512 threads = 8 independent waves.
// Each wave: 16 rows x 48 cols. A from packed bits (expand in reg),
// B fragments straight from Bmat via L2. Ping-pong register double-buffer.
__global__ __launch_bounds__(512, 4) void k2_gemm(
        const unsigned long long* __restrict__ packed,
        const ushort* __restrict__ Bmat,
        float* __restrict__ Cpart) {
    const int tid = threadIdx.x;
    const int wid = tid >> 6;
    const int lane = tid & 63;
    const int fr = lane & 15;
    const int fg = lane >> 4;

    const int row0 = blockIdx.x * 64;
    const int seg = blockIdx.y >> 1;
    const int ch  = blockIdx.y & 1;

    const int wrow = (wid & 3) * 16;
    const int wcol = ch * 96 + (wid >> 2) * 48;

    const int arow = row0 + wrow + fr;
    const unsigned long long* pA = packed + (size_t)arow * NWORDS + seg * STEPS;

    const ushort* Bb[3];
    #pragma unroll
    for (int n = 0; n < 3; ++n)
        Bb[n] = Bmat + (size_t)(wcol + n * 16 + fr) * DPAD + seg * KSEG + fg * 8;

    f32x4 acc[3] = {};

    uint2 awA, awB;
    uint4 pbA[6], pbB[6];

    // prologue: load step 0 into A-buffers
    awA = *reinterpret_cast<const uint2*>(&pA[0]);
    #pragma unroll
    for (int n = 0; n < 3; ++n) {
        pbA[n * 2 + 0] = *reinterpret_cast<const uint4*>(Bb[n] + 0);
        pbA[n * 2 + 1] = *reinterpret_cast<const uint4*>(Bb[n] + 32);
    }

    for (int s = 0; s < STEPS; s += 2) {
        // prefetch step s+1 into B-buffers (always valid: s+1 <= 39)
        {
            const int s1 = s + 1;
            awB = *reinterpret_cast<const uint2*>(&pA[s1]);
            #pragma unroll
            for (int n = 0; n < 3; ++n) {
                pbB[n * 2 + 0] = *reinterpret_cast<const uint4*>(Bb[n] + s1 * 64 + 0);
                pbB[n * 2 + 1] = *reinterpret_cast<const uint4*>(Bb[n] + s1 * 64 + 32);
            }
        }
        // compute step s from A-buffers
        {
            short8 af0 = expand8((awA.x >> (fg * 8)) & 0xffu);
            short8 af1 = expand8((awA.y >> (fg * 8)) & 0xffu);
            #pragma unroll
            for (int n = 0; n < 3; ++n) {
                acc[n] = __builtin_amdgcn_mfma_f32_16x16x32_bf16(
                    af0, __builtin_bit_cast(short8, pbA[n * 2 + 0]), acc[n], 0, 0, 0);
                acc[n] = __builtin_amdgcn_mfma_f32_16x16x32_bf16(
                    af1, __builtin_bit_cast(short8, pbA[n * 2 + 1]), acc[n], 0, 0, 0);
            }
        }
        // prefetch step s+2 into A-buffers (clamped; redundant at tail)
        {
            const int s2 = (s + 2 < STEPS) ? (s + 2) : (STEPS - 1);
            awA = *reinterpret_cast<const uint2*>(&pA[s2]);
            #pragma unroll
            for (int n = 0; n < 3; ++n) {
                pbA[n * 2 + 0] = *reinterpret_cast<const uint4*>(Bb[n] + s2 * 64 + 0);
                pbA[n * 2 + 1] = *reinterpret_cast<const uint4*>(Bb[n] + s2 * 64 + 32);
            }
        }
        // compute step s+1 from B-buffers
        {
            short8 af0 = expand8((awB.x >> (fg * 8)) & 0xffu);
            short8 af1 = expand8((awB.y >> (fg * 8)) & 0xffu);
            #pragma unroll
            for (int n = 0; n < 3; ++n) {
                acc[n] = __builtin_amdgcn_mfma_f32_16x16x32_bf16(
                    af0, __builtin_bit_cast(short8, pbB[n * 2 + 0]), acc[n], 0, 0, 0);
                acc[n] = __builtin_amdgcn_mfma_f32_16x16x32_bf16(
                    af1, __builtin_bit_cast(short8, pbB[n * 2 + 1]), acc[n], 0, 0, 0);
            }
        }
    }

    // epilogue: D col=lane&15, row=(lane>>4)*4+reg
    #pragma unroll
    for (int n = 0; n < 3; ++n)
        #pragma unroll
        for (int r = 0; r < 4; ++r) {
            int grow = row0 + wrow + fg * 4 + r;
            int col = wcol + n * 16 + fr;
            Cpart[((size_t)seg * BB + grow) * NROWS_B + col] = acc[n][r];
        }
}

// ---------------- K3: reduce partials + softmax + combine ----------------
__global__ __launch_bounds__(256) void k3_final(
        const float* __restrict__ Cpart, float* __restrict__ res) {
    const int wid = threadIdx.x >> 6;
    const int lane = threadIdx.x & 63;
    const int row = blockIdx.x * 4 + wid;

    float s = 0.f, mh = 0.f, ml = 0.f;
    #pragma unroll
    for (int seg = 0; seg < KSPLIT; ++seg) {
        const float* base = Cpart + ((size_t)seg * BB + row) * NROWS_B;
        s += base[lane];
        mh += base[64 + lane];
        ml += base[128 + lane];
    }
    float sim = s * 1e-4f;          // exact norms: 100 * 100
    float mr = mh + ml;

    float mx = sim;
    #pragma unroll
    for (int o = 32; o; o >>= 1) mx = fmaxf(mx, __shfl_xor(mx, o, 64));
    float e = expf(sim - mx);
    float num = e * mr;
    float Z = e;
    #pragma unroll
    for (int o = 32; o; o >>= 1) {
        Z += __shfl_xor(Z, o, 64);
        num += __shfl_xor(num, o, 64);
    }
    if (lane == 0) res[row] = num / Z;
}

extern "C" void kernel_launch(void* const* d_in, const int* in_sizes, int n_in,
                              void* d_out, int out_size, void* d_ws, size_t ws_size,
                              hipStream_t stream) {
    const float* x = (const float*)d_in[0];
    const float* W = (const float*)d_in[1];
    const float* bias = (const float*)d_in[2];
    const float* M = (const float*)d_in[3];
    const float* cluster = (const float*)d_in[4];

    float* res = (float*)d_out;            // [4096]
    float* enc = (float*)d_out + BB;       // [4096][10000]

    ushort* Bmat = (ushort*)((char*)d_ws + WS_BMAT_OFF);              // 3.93 MB
    unsigned long long* packed = (unsigned long long*)((char*)d_ws + WS_PACK_OFF);  // 5.24 MB
    float* Cpart = (float*)((char*)d_ws + WS_CPART_OFF);              // 12.6 MB

    k0_build_B<<<dim3(40, 192), 256, 0, stream>>>(M, cluster, Bmat);
    k1_enc<<<dim3(40, 64), 256, 0, stream>>>(x, W, bias, enc, packed);
    k2_gemm<<<dim3(64, 8), 512, 0, stream>>>(packed, Bmat, Cpart);
    k3_final<<<BB / 4, 256, 0, stream>>>(Cpart, res);
}

// Round 14
// 128.358 us; speedup vs baseline: 1.8161x; 1.6782x over previous
//
#include <hip/hip_runtime.h>
#include <hip/hip_bf16.h>

#define BB 4096
#define SZ 32
#define DD 10000
#define DPAD 10240
#define NMOD 64
#define NROWS_B 192   // cluster(64) + Mh(64) + Ml(64)
#define KSPLIT 4
#define KSEG 2560     // DPAD / KSPLIT
#define NWORDS 160    // DPAD/64 packed words per row
#define STEPS 40      // KSEG/64

// ws layout (bytes)
#define WS_BK_OFF     0u                         // 160*192*64*2 = 3.93 MB
#define WS_PACK_OFF   (4u << 20)                 // 160*4096*8 = 5.24 MB
#define WS_CPART_OFF  (9437184u)                 // 4*4096*192*4 = 12.6 MB

typedef __attribute__((ext_vector_type(4))) float f32x4;
typedef __attribute__((ext_vector_type(8))) short short8;

static __device__ __forceinline__ ushort f2bf(float f) {
    unsigned u = __builtin_bit_cast(unsigned, f);
    unsigned r = (u + 0x7fffu + ((u >> 16) & 1u)) >> 16;   // RNE
    return (ushort)r;
}

// sign pipeline: 1 iff cosf(t+bk)*sinf(t) > 0, else 0 (covers ==0 -> -1).
static __device__ __forceinline__ int sign_pm(float t, float bk) {
    if (t == 0.0f) return 0;                 // sin(+-0)=+-0 -> sample==+-0 -> -1
    const double INV_PI_D = 0.31830988618379067153776752674503;
    float v = t + bk;
    long long n1 = (long long)floor((double)t * INV_PI_D);
    long long n2 = (long long)floor(fma((double)v, INV_PI_D, 0.5));
    return (int)(((n1 + n2) & 1LL) ^ 1LL);   // 1 -> +1, 0 -> -1
}

// expand 8 packed bits (bit=1 -> +1.0bf16, 0 -> -1.0bf16) into short8
static __device__ __forceinline__ short8 expand8(unsigned b) {
    unsigned nb = ~b;
    unsigned r0 = 0x3F803F80u | ((nb & 1u) << 15) | ((nb & 2u) << 30);
    unsigned r1 = 0x3F803F80u | (((nb >> 2) & 1u) << 15) | (((nb >> 2) & 2u) << 30);
    unsigned r2 = 0x3F803F80u | (((nb >> 4) & 1u) << 15) | (((nb >> 4) & 2u) << 30);
    unsigned r3 = 0x3F803F80u | (((nb >> 6) & 1u) << 15) | (((nb >> 6) & 2u) << 30);
    uint4 u = make_uint4(r0, r1, r2, r3);
    return __builtin_bit_cast(short8, u);
}

// ---------------- K0: build Bk [160 steps][192 rows][64 k] bf16 -----------
__global__ __launch_bounds__(256) void k0_build_B(
        const float* __restrict__ M, const float* __restrict__ cluster,
        ushort* __restrict__ Bk) {
    int k = blockIdx.x * 256 + threadIdx.x;   // 0..10239
    int row = blockIdx.y;                      // 0..191
    ushort u = 0;
    if (k < DD) {
        if (row < 64) {
            u = f2bf(cluster[row * DD + k]);
        } else {
            float m = M[(row & 63) * DD + k];
            ushort mh = f2bf(m);
            if (row < 128) {
                u = mh;
            } else {
                float mhf = __builtin_bit_cast(float, (unsigned)mh << 16);
                u = f2bf(m - mhf);
            }
        }
    }
    int step = k >> 6, kk = k & 63;
    Bk[((size_t)step * NROWS_B + row) * 64 + kk] = u;
}

// ---------------- K1: encode (T_G ordering) -> enc f32 + packedT ----------
__global__ __launch_bounds__(256) void k1_enc(
        const float* __restrict__ x, const float* __restrict__ W,
        const float* __restrict__ bias, float* __restrict__ enc_out,
        unsigned long long* __restrict__ packedT) {
    __shared__ float xs[64 * SZ];
    const int tid = threadIdx.x;
    const int i0 = blockIdx.y * 64;
    const int k = blockIdx.x * 256 + tid;
    const bool valid = (k < DD);
    const int lane = tid & 63;
    const int word = blockIdx.x * 4 + (tid >> 6);  // packed word index 0..159

    {
        const float4* xg = reinterpret_cast<const float4*>(x + (size_t)i0 * SZ);
        float4* xs4 = reinterpret_cast<float4*>(xs);
        xs4[tid] = xg[tid];
        xs4[tid + 256] = xg[tid + 256];
    }
    const int kw = valid ? k : 0;
    float4 w4[8];
    {
        const float4* wg = reinterpret_cast<const float4*>(W) + (size_t)kw * 8;
        #pragma unroll
        for (int c = 0; c < 8; ++c) w4[c] = wg[c];
    }
    const float bk = bias[kw];
    __syncthreads();

    for (int i = 0; i < 64; ++i) {
        const float4* xr = reinterpret_cast<const float4*>(xs + i * SZ);
        float g0 = 0.f, g1 = 0.f, g2 = 0.f, g3 = 0.f;
        #pragma unroll
        for (int c = 0; c < 8; ++c) {
            float4 xc = xr[c];   // LDS broadcast (uniform address)
            g0 = fmaf(w4[c].x, xc.x, g0);
            g1 = fmaf(w4[c].y, xc.y, g1);
            g2 = fmaf(w4[c].z, xc.z, g2);
            g3 = fmaf(w4[c].w, xc.w, g3);
        }
        float t = (g0 + g1) + (g2 + g3);
        int e = sign_pm(t, bk);
        unsigned long long m = __ballot(e);
        if (valid) enc_out[(size_t)(i0 + i) * DD + k] = e ? 1.f : -1.f;
        if (lane == 0) packedT[(size_t)word * BB + (i0 + i)] = m;
    }
}

// ---------------- K2: fragment-direct MFMA GEMM (no LDS, no barriers) -----
// grid (64 row-groups, 4 segs), 256 thr = 4 waves = 4 col-groups of 48 cols.
// Each wave: 64 rows (4 mfma row-tiles) x 48 cols, K = 2560.
__global__ __launch_bounds__(256, 2) void k2_gemm(
        const unsigned long long* __restrict__ packedT,  // [160][4096]
        const ushort* __restrict__ Bk,                   // [160][192][64]
        float* __restrict__ Cpart) {
    const int tid = threadIdx.x;
    const int wid = tid >> 6;       // col-group 0..3
    const int lane = tid & 63;
    const int fr = lane & 15;
    const int fg = lane >> 4;

    const int row0 = blockIdx.x * 64;
    const int seg = blockIdx.y;
    const int wcol = wid * 48;

    // A: packedT[(seg*40+s)*4096 + row0 + mt*16 + fr]
    const unsigned long long* pA = packedT + (size_t)(seg * STEPS) * BB + row0 + fr;
    // B: Bk[((seg*40+s)*192 + wcol + n*16 + fr)*64 + fg*8 (+32)]
    const ushort* pB = Bk + ((size_t)(seg * STEPS) * NROWS_B + wcol + fr) * 64 + fg * 8;

    f32x4 acc[4][3] = {};
    unsigned long long aw0[4], aw1[4];
    uint4 b0[3][2], b1[3][2];

#define LOADA(dst, s)                                         \
    _Pragma("unroll")                                         \
    for (int mt = 0; mt < 4; ++mt)                            \
        dst[mt] = pA[(size_t)(s) * BB + mt * 16];

#define LOADB(dst, s)                                         \
    _Pragma("unroll")                                         \
    for (int n = 0; n < 3; ++n) {                             \
        const ushort* p = pB + ((size_t)(s) * NROWS_B + n * 16) * 64; \
        dst[n][0] = *reinterpret_cast<const uint4*>(p);       \
        dst[n][1] = *reinterpret_cast<const uint4*>(p + 32);  \
    }

#define COMPUTE(aw, bf)                                       \
    _Pragma("unroll")                                         \
    for (int mt = 0; mt < 4; ++mt) {                          \
        unsigned lo = (unsigned)aw[mt];                       \
        unsigned hi = (unsigned)(aw[mt] >> 32);               \
        short8 af0 = expand8((lo >> (fg * 8)) & 0xffu);       \
        short8 af1 = expand8((hi >> (fg * 8)) & 0xffu);       \
        _Pragma("unroll")                                     \
        for (int n = 0; n < 3; ++n) {                         \
            acc[mt][n] = __builtin_amdgcn_mfma_f32_16x16x32_bf16( \
                af0, __builtin_bit_cast(short8, bf[n][0]), acc[mt][n], 0, 0, 0); \
            acc[mt][n] = __builtin_amdgcn_mfma_f32_16x16x32_bf16( \
                af1, __builtin_bit_cast(short8, bf[n][1]), acc[mt][n], 0, 0, 0); \
        }                                                     \
    }

    LOADA(aw0, 0)
    LOADB(b0, 0)

    for (int s = 0; s < STEPS; s += 2) {
        LOADA(aw1, s + 1)
        LOADB(b1, s + 1)
        COMPUTE(aw0, b0)
        if (s + 2 < STEPS) {
            LOADA(aw0, s + 2)
            LOADB(b0, s + 2)
        }
        COMPUTE(aw1, b1)
    }

    // epilogue: D col=lane&15, row=(lane>>4)*4+reg
    #pragma unroll
    for (int mt = 0; mt < 4; ++mt)
        #pragma unroll
        for (int n = 0; n < 3; ++n)
            #pragma unroll
            for (int r = 0; r < 4; ++r) {
                int grow = row0 + mt * 16 + fg * 4 + r;
                int col = wcol + n * 16 + fr;
                Cpart[((size_t)seg * BB + grow) * NROWS_B + col] = acc[mt][n][r];
            }
#undef LOADA
#undef LOADB
#undef COMPUTE
}

// ---------------- K3: reduce partials + softmax + combine ----------------
__global__ __launch_bounds__(256) void k3_final(
        const float* __restrict__ Cpart, float* __restrict__ res) {
    const int wid = threadIdx.x >> 6;
    const int lane = threadIdx.x & 63;
    const int row = blockIdx.x * 4 + wid;

    float s = 0.f, mh = 0.f, ml = 0.f;
    #pragma unroll
    for (int seg = 0; seg < KSPLIT; ++seg) {
        const float* base = Cpart + ((size_t)seg * BB + row) * NROWS_B;
        s += base[lane];
        mh += base[64 + lane];
        ml += base[128 + lane];
    }
    float sim = s * 1e-4f;          // exact norms: 100 * 100
    float mr = mh + ml;

    float mx = sim;
    #pragma unroll
    for (int o = 32; o; o >>= 1) mx = fmaxf(mx, __shfl_xor(mx, o, 64));
    float e = expf(sim - mx);
    float num = e * mr;
    float Z = e;
    #pragma unroll
    for (int o = 32; o; o >>= 1) {
        Z += __shfl_xor(Z, o, 64);
        num += __shfl_xor(num, o, 64);
    }
    if (lane == 0) res[row] = num / Z;
}

extern "C" void kernel_launch(void* const* d_in, const int* in_sizes, int n_in,
                              void* d_out, int out_size, void* d_ws, size_t ws_size,
                              hipStream_t stream) {
    const float* x = (const float*)d_in[0];
    const float* W = (const float*)d_in[1];
    const float* bias = (const float*)d_in[2];
    const float* M = (const float*)d_in[3];
    const float* cluster = (const float*)d_in[4];

    float* res = (float*)d_out;            // [4096]
    float* enc = (float*)d_out + BB;       // [4096][10000]

    ushort* Bk = (ushort*)((char*)d_ws + WS_BK_OFF);
    unsigned long long* packedT = (unsigned long long*)((char*)d_ws + WS_PACK_OFF);
    float* Cpart = (float*)((char*)d_ws + WS_CPART_OFF);

    k0_build_B<<<dim3(40, 192), 256, 0, stream>>>(M, cluster, Bk);
    k1_enc<<<dim3(40, 64), 256, 0, stream>>>(x, W, bias, enc, packedT);
    k2_gemm<<<dim3(64, KSPLIT), 256, 0, stream>>>(packedT, Bk, Cpart);
    k3_final<<<BB / 4, 256, 0, stream>>>(Cpart, res);
}